// Round 1
// baseline (171.165 us; speedup 1.0000x reference)
//
#include <hip/hip_runtime.h>
#include <math.h>

// Problem constants (from reference): B=8192 batches, N=1024 points each.
constexpr int B_ = 8192;
constexpr int N_ = 1024;
constexpr int NTHREADS = 256;
constexpr int BATCHES_PER_BLOCK = 4;           // 2048 blocks -> 8/CU resident (wave-limited)
constexpr int NBLOCKS = B_ / BATCHES_PER_BLOCK;

// R = Rx(a) @ Ry(b) @ Rz(c), row-major 3x3 (matches reference euler_to_matrix_xyz)
__device__ __forceinline__ void euler_to_mat(float a, float b, float c, float R[9]) {
    float ca = cosf(a), sa = sinf(a);
    float cb = cosf(b), sb = sinf(b);
    float cc = cosf(c), sc = sinf(c);
    R[0] = cb * cc;             R[1] = -cb * sc;            R[2] = sb;
    R[3] = ca * sc + sa * sb * cc; R[4] = ca * cc - sa * sb * sc; R[5] = -sa * cb;
    R[6] = sa * sc - ca * sb * cc; R[7] = sa * cc + ca * sb * sc; R[8] = ca * cb;
}

__global__ __launch_bounds__(NTHREADS)
void add_loss_kernel(const float* __restrict__ pred,   // (B,4)
                     const float* __restrict__ mode,   // (B,)
                     const float* __restrict__ gt,     // (B,3)
                     const float* __restrict__ point,  // (B,N,3)
                     float* __restrict__ out)          // scalar (pre-zeroed)
{
    __shared__ float sM[9];
    __shared__ float spts[N_ * 3];              // 12 KB point stage
    __shared__ float swave[NTHREADS / 64];

    const int tid = threadIdx.x;
    float local = 0.0f;

    for (int ib = 0; ib < BATCHES_PER_BLOCK; ++ib) {
        const int b = blockIdx.x * BATCHES_PER_BLOCK + ib;

        // --- stage this batch's points: 768 float4s, fully coalesced ---
        const float4* gp = (const float4*)(point + (size_t)b * (N_ * 3));
        float4* sp4 = (float4*)spts;
        #pragma unroll
        for (int i = 0; i < (N_ * 3 / 4) / NTHREADS; ++i)
            sp4[tid + NTHREADS * i] = gp[tid + NTHREADS * i];

        // --- thread 0: M = R(pred-euler) - R(gt), overlapped with staging ---
        if (tid == 0) {
            float m1 = pred[b * 4 + 0], m2 = pred[b * 4 + 1];
            float m3 = pred[b * 4 + 2], m4 = pred[b * 4 + 3];
            float sgn = (mode[b] > 0.5f) ? 1.0f : -1.0f;
            float e2 = sgn * asinf(sqrtf(m3 * m3 / (m1 * m1 + m2 * m2 + m3 * m3)));
            float e3 = atan2f(m4, m3 / (sinf(e2) + 1e-9f));
            float tmp = cosf(e2) * cosf(e3);
            float e1 = atan2f(m2 / tmp, m1 / tmp);
            e3 = (e3 > 0.0f) ? e3 : (e3 + 6.2831854820251465f); // float32(2*pi)
            float P[9], G[9];
            euler_to_mat(e1, e2, e3, P);
            euler_to_mat(gt[b * 3 + 0], gt[b * 3 + 1], gt[b * 3 + 2], G);
            #pragma unroll
            for (int i = 0; i < 9; ++i) sM[i] = P[i] - G[i];
        }
        __syncthreads();

        const float M0 = sM[0], M1 = sM[1], M2 = sM[2];
        const float M3 = sM[3], M4 = sM[4], M5 = sM[5];
        const float M6 = sM[6], M7 = sM[7], M8 = sM[8];

        // --- per-point: diff = p . M ; dist = |diff| ---
        // n = tid + 256*i -> LDS float stride 3 across lanes: gcd(3,32)=1,
        // 2 lanes/bank = free on gfx950 (m136).
        #pragma unroll
        for (int i = 0; i < N_ / NTHREADS; ++i) {
            int n = tid + NTHREADS * i;
            float px = spts[3 * n + 0], py = spts[3 * n + 1], pz = spts[3 * n + 2];
            float dx = px * M0 + py * M3 + pz * M6;
            float dy = px * M1 + py * M4 + pz * M7;
            float dz = px * M2 + py * M5 + pz * M8;
            local += sqrtf(dx * dx + dy * dy + dz * dz);
        }
        __syncthreads();   // protect spts/sM before next iteration overwrites
    }

    // --- block reduction: wave64 shuffle -> LDS -> one atomic per block ---
    #pragma unroll
    for (int off = 32; off > 0; off >>= 1)
        local += __shfl_down(local, off, 64);
    if ((tid & 63) == 0) swave[tid >> 6] = local;
    __syncthreads();
    if (tid == 0) {
        float s = swave[0] + swave[1] + swave[2] + swave[3];
        atomicAdd(out, s * (1.0f / ((float)B_ * (float)N_)));
    }
}

extern "C" void kernel_launch(void* const* d_in, const int* in_sizes, int n_in,
                              void* d_out, int out_size, void* d_ws, size_t ws_size,
                              hipStream_t stream) {
    const float* pred  = (const float*)d_in[0];
    const float* mode  = (const float*)d_in[1];
    const float* gt    = (const float*)d_in[2];
    const float* point = (const float*)d_in[3];
    float* out = (float*)d_out;

    // d_out is poisoned 0xAA before every timed launch — zero it (capture-safe).
    hipMemsetAsync(out, 0, sizeof(float), stream);
    add_loss_kernel<<<NBLOCKS, NTHREADS, 0, stream>>>(pred, mode, gt, point, out);
}

// Round 2
// 153.801 us; speedup vs baseline: 1.1129x; 1.1129x over previous
//
#include <hip/hip_runtime.h>
#include <math.h>

constexpr int B_ = 8192;
constexpr int N_ = 1024;
constexpr int NTHREADS = 256;         // 4 points/thread in point_kernel
constexpr float SCALE = 1.0f / ((float)B_ * (float)N_);

// R = Rx(a) @ Ry(b) @ Rz(c), row-major 3x3 (matches reference euler_to_matrix_xyz)
__device__ __forceinline__ void euler_to_mat(float a, float b, float c, float R[9]) {
    float ca = cosf(a), sa = sinf(a);
    float cb = cosf(b), sb = sinf(b);
    float cc = cosf(c), sc = sinf(c);
    R[0] = cb * cc;                R[1] = -cb * sc;               R[2] = sb;
    R[3] = ca * sc + sa * sb * cc; R[4] = ca * cc - sa * sb * sc; R[5] = -sa * cb;
    R[6] = sa * sc - ca * sb * cc; R[7] = sa * cc + ca * sb * sc; R[8] = ca * cb;
}

// M[b] = R(euler(pred[b], mode[b])) - R(gt[b]) — same fp32 ops as the passing R1 kernel.
__device__ __forceinline__ void compute_M(const float* __restrict__ pred,
                                          const float* __restrict__ mode,
                                          const float* __restrict__ gt,
                                          int b, float M[9]) {
    float m1 = pred[b * 4 + 0], m2 = pred[b * 4 + 1];
    float m3 = pred[b * 4 + 2], m4 = pred[b * 4 + 3];
    float sgn = (mode[b] > 0.5f) ? 1.0f : -1.0f;
    float e2 = sgn * asinf(sqrtf(m3 * m3 / (m1 * m1 + m2 * m2 + m3 * m3)));
    float e3 = atan2f(m4, m3 / (sinf(e2) + 1e-9f));
    float tmp = cosf(e2) * cosf(e3);
    float e1 = atan2f(m2 / tmp, m1 / tmp);
    e3 = (e3 > 0.0f) ? e3 : (e3 + 6.2831854820251465f); // float32(2*pi)
    float P[9], G[9];
    euler_to_mat(e1, e2, e3, P);
    euler_to_mat(gt[b * 3 + 0], gt[b * 3 + 1], gt[b * 3 + 2], G);
    #pragma unroll
    for (int i = 0; i < 9; ++i) M[i] = P[i] - G[i];
}

// ---------- Phase 1: all-lanes-parallel M computation (8192 threads) ----------
__global__ __launch_bounds__(256)
void prep_M_kernel(const float* __restrict__ pred, const float* __restrict__ mode,
                   const float* __restrict__ gt, float* __restrict__ Mout) {
    int b = blockIdx.x * blockDim.x + threadIdx.x;
    if (b >= B_) return;
    float M[9];
    compute_M(pred, mode, gt, b, M);
    #pragma unroll
    for (int i = 0; i < 9; ++i) Mout[b * 9 + i] = M[i];
}

__device__ __forceinline__ float dist3(float px, float py, float pz, const float M[9]) {
    float dx = px * M[0] + py * M[3] + pz * M[6];
    float dy = px * M[1] + py * M[4] + pz * M[7];
    float dz = px * M[2] + py * M[5] + pz * M[8];
    return sqrtf(dx * dx + dy * dy + dz * dz);
}

// ---------- Phase 2: streaming point kernel, one block per batch ----------
__global__ __launch_bounds__(NTHREADS)
void point_kernel(const float* __restrict__ point,   // (B,N,3)
                  const float* __restrict__ Mg,      // (B,9)
                  float* __restrict__ partial)       // (B,)
{
    const int b = blockIdx.x;
    const int t = threadIdx.x;
    __shared__ float sM[9];
    __shared__ float swave[NTHREADS / 64];

    if (t < 9) sM[t] = Mg[b * 9 + t];
    __syncthreads();
    float M[9];
    #pragma unroll
    for (int i = 0; i < 9; ++i) M[i] = sM[i];

    // 3 consecutive float4 loads = 12 contiguous floats = 4 whole points.
    // Wave covers a contiguous 3 KB region; every fetched line fully used.
    const float4* gp = (const float4*)(point + (size_t)b * (N_ * 3));
    float4 p0 = gp[3 * t + 0];
    float4 p1 = gp[3 * t + 1];
    float4 p2 = gp[3 * t + 2];

    float local = dist3(p0.x, p0.y, p0.z, M)
                + dist3(p0.w, p1.x, p1.y, M)
                + dist3(p1.z, p1.w, p2.x, M)
                + dist3(p2.y, p2.z, p2.w, M);

    #pragma unroll
    for (int off = 32; off > 0; off >>= 1)
        local += __shfl_down(local, off, 64);
    if ((t & 63) == 0) swave[t >> 6] = local;
    __syncthreads();
    if (t == 0) partial[b] = swave[0] + swave[1] + swave[2] + swave[3];
}

// ---------- Phase 3: reduce 8192 partials -> scalar ----------
__global__ __launch_bounds__(1024)
void reduce_kernel(const float* __restrict__ partial, float* __restrict__ out) {
    __shared__ float swave[1024 / 64];
    const int t = threadIdx.x;
    float local = 0.0f;
    #pragma unroll
    for (int i = 0; i < B_ / 1024; ++i) local += partial[t + 1024 * i];
    #pragma unroll
    for (int off = 32; off > 0; off >>= 1)
        local += __shfl_down(local, off, 64);
    if ((t & 63) == 0) swave[t >> 6] = local;
    __syncthreads();
    if (t == 0) {
        float s = 0.0f;
        #pragma unroll
        for (int i = 0; i < 1024 / 64; ++i) s += swave[i];
        out[0] = s * SCALE;
    }
}

// ---------- Fallback (ws too small): fused, redundant per-thread M ----------
__global__ __launch_bounds__(NTHREADS)
void fused_kernel(const float* __restrict__ pred, const float* __restrict__ mode,
                  const float* __restrict__ gt, const float* __restrict__ point,
                  float* __restrict__ out) {
    const int b = blockIdx.x;
    const int t = threadIdx.x;
    __shared__ float swave[NTHREADS / 64];
    float M[9];
    compute_M(pred, mode, gt, b, M);   // all threads redundantly — no serialization
    const float4* gp = (const float4*)(point + (size_t)b * (N_ * 3));
    float4 p0 = gp[3 * t + 0];
    float4 p1 = gp[3 * t + 1];
    float4 p2 = gp[3 * t + 2];
    float local = dist3(p0.x, p0.y, p0.z, M)
                + dist3(p0.w, p1.x, p1.y, M)
                + dist3(p1.z, p1.w, p2.x, M)
                + dist3(p2.y, p2.z, p2.w, M);
    #pragma unroll
    for (int off = 32; off > 0; off >>= 1)
        local += __shfl_down(local, off, 64);
    if ((t & 63) == 0) swave[t >> 6] = local;
    __syncthreads();
    if (t == 0)
        atomicAdd(out, (swave[0] + swave[1] + swave[2] + swave[3]) * SCALE);
}

extern "C" void kernel_launch(void* const* d_in, const int* in_sizes, int n_in,
                              void* d_out, int out_size, void* d_ws, size_t ws_size,
                              hipStream_t stream) {
    const float* pred  = (const float*)d_in[0];
    const float* mode  = (const float*)d_in[1];
    const float* gt    = (const float*)d_in[2];
    const float* point = (const float*)d_in[3];
    float* out = (float*)d_out;

    const size_t need = (size_t)(B_ * 9 + B_) * sizeof(float); // M (288 KB) + partials (32 KB)
    if (ws_size >= need) {
        float* Mg      = (float*)d_ws;
        float* partial = Mg + B_ * 9;
        prep_M_kernel<<<B_ / 256, 256, 0, stream>>>(pred, mode, gt, Mg);
        point_kernel<<<B_, NTHREADS, 0, stream>>>(point, Mg, partial);
        reduce_kernel<<<1, 1024, 0, stream>>>(partial, out);
    } else {
        hipMemsetAsync(out, 0, sizeof(float), stream);
        fused_kernel<<<B_, NTHREADS, 0, stream>>>(pred, mode, gt, point, out);
    }
}